// Round 1
// baseline (45.624 us; speedup 1.0000x reference)
//
#include <hip/hip_runtime.h>

// out[b, k] = in[b, TRI_I[k]] * in[b, TRI_J[k]], k over strictly-lower-tri
// (i>j) pairs of a 512x512 matrix in row-major (i,j) order.
// B=512, N=512, NC2 = 512*511/2 = 130816.

#define N_ATOMS 512
#define NC2     130816
#define NQ4     (NC2 / 4)   // 32704 float4 stores per batch row

__global__ __launch_bounds__(256) void ncp_kernel(const float* __restrict__ in,
                                                  float* __restrict__ out) {
    __shared__ float row[N_ATOMS];
    const int b   = blockIdx.y;
    const int tid = threadIdx.x;

    // Stage this batch's 512-float row into LDS (256 threads x float2).
    const float2* src = reinterpret_cast<const float2*>(in + (size_t)b * N_ATOMS);
    reinterpret_cast<float2*>(row)[tid] = src[tid];
    __syncthreads();

    float4* outb = reinterpret_cast<float4*>(out + (size_t)b * NC2);

    for (int q = blockIdx.x * 256 + tid; q < NQ4; q += gridDim.x * 256) {
        const int k = q * 4;

        // i = row index of flat tri element k: floor((1 + sqrt(8k+1)) / 2),
        // then integer fix-up for sqrtf rounding at triangular boundaries.
        int i = (int)(0.5f * (1.0f + sqrtf(8.0f * (float)k + 1.0f)));
        while (i * (i - 1) / 2 > k)       --i;
        while ((i + 1) * i / 2 <= k)      ++i;
        int j = k - i * (i - 1) / 2;

        float4 v;
        float* vp = &v.x;
#pragma unroll
        for (int t = 0; t < 4; ++t) {
            vp[t] = row[i] * row[j];
            if (++j == i) { ++i; j = 0; }   // advance to next tri pair
        }
        outb[q] = v;
    }
}

extern "C" void kernel_launch(void* const* d_in, const int* in_sizes, int n_in,
                              void* d_out, int out_size, void* d_ws, size_t ws_size,
                              hipStream_t stream) {
    const float* atom_nc = (const float*)d_in[0];
    float* out = (float*)d_out;

    dim3 grid(32, 512);   // 32 chunks per batch x 512 batches
    dim3 block(256);
    ncp_kernel<<<grid, block, 0, stream>>>(atom_nc, out);
}